// Round 4
// baseline (151.771 us; speedup 1.0000x reference)
//
#include <hip/hip_runtime.h>
#include <hip/hip_bf16.h>

#define NB 8
#define NS 4096
#define ND 64
#define NROW (NB * NS)
#define NTILE (NS / 64)

typedef short v4s __attribute__((ext_vector_type(4)));
typedef short v8s __attribute__((ext_vector_type(8)));
typedef float v4f __attribute__((ext_vector_type(4)));

static __device__ __forceinline__ v4s pk4(float a, float b, float c, float d) {
    union { __hip_bfloat162 h[2]; v4s v; } u;
    float2 p0; p0.x = a; p0.y = b;
    float2 p1; p1.x = c; p1.y = d;
    u.h[0] = __float22bfloat162_rn(p0);
    u.h[1] = __float22bfloat162_rn(p1);
    return u.v;
}
static __device__ __forceinline__ v8s pk8(v4f x0, v4f x1) {
    union { v4s q[2]; v8s v; } u;
    u.q[0] = pk4(x0[0], x0[1], x0[2], x0[3]);
    u.q[1] = pk4(x1[0], x1[1], x1[2], x1[3]);
    return u.v;
}
static __device__ __forceinline__ float b2f(short s) {
    return __uint_as_float(((unsigned)(unsigned short)s) << 16);
}

__device__ __forceinline__ void gl16(const void* g, void* s) {
    __builtin_amdgcn_global_load_lds(
        (const __attribute__((address_space(1))) void*)g,
        (__attribute__((address_space(3))) void*)s, 16, 0, 0);
}

// ---- fused prepass: K -> bf16 swizzled tiles; V -> bf16 transposed tiles ----
__global__ __launch_bounds__(256) void prep_kv(const float* __restrict__ K,
        const float* __restrict__ V, short* __restrict__ Kb,
        short* __restrict__ Vt) {
    __shared__ short T[64][72];
    const int t = threadIdx.x;
    if (blockIdx.x < 1024) {
        // K: per-64-key-tile stream, 16B granules XOR-swizzled by row
        size_t n = (size_t)blockIdx.x * 256 + t;
        int g = (int)(n & 7);
        size_t r = n >> 3;
        int row = (int)(r & 63);
        size_t tile = r >> 6;
        v4f x0 = *(const v4f*)(K + n * 8);
        v4f x1 = *(const v4f*)(K + n * 8 + 4);
        *(v8s*)&Kb[tile * 4096 + row * 64 + ((g ^ (row & 7)) << 3)] = pk8(x0, x1);
    } else {
        // V: transpose [d][key] per tile, swizzled granules
        const int bt = blockIdx.x - 1024;
        const int b  = bt >> 6;
        const int s0 = (bt & 63) * 64;
        #pragma unroll
        for (int i = 0; i < 2; ++i) {
            int n = i * 256 + t;
            int r = n >> 3, c8 = (n & 7) * 8;
            const float* src = V + ((size_t)b * NS + s0 + r) * ND + c8;
            v4f x0 = *(const v4f*)src;
            v4f x1 = *(const v4f*)(src + 4);
            *(v8s*)&T[r][c8] = pk8(x0, x1);
        }
        __syncthreads();
        #pragma unroll
        for (int i = 0; i < 2; ++i) {
            int n = i * 256 + t;
            int d = n >> 3, kg = n & 7;
            v8s a;
            #pragma unroll
            for (int j = 0; j < 8; ++j) a[j] = T[kg * 8 + j][d];
            *(v8s*)&Vt[(size_t)bt * 4096 + d * 64 + ((kg ^ (d & 7)) << 3)] = a;
        }
    }
}

// ---- main flash kernel: 32 q/wave, 128 q/block, split-K ----
template <int SPLIT>
__global__ __launch_bounds__(256, 5) void fa_main(
        const float* __restrict__ Q, const short* __restrict__ Kbf,
        const short* __restrict__ Vtb, float* __restrict__ O,
        short* __restrict__ Opart, float2* __restrict__ stats) {
    __shared__ short Ksh[2][4096];
    __shared__ short Vsh[2][4096];

    const int t    = threadIdx.x;
    const int lane = t & 63;
    const int w    = t >> 6;
    const int lc   = lane & 15;
    const int h    = lane >> 4;
    const int lw   = lc & 7;

    const int bid  = blockIdx.x;
    const int b    = bid & 7;                 // batch -> XCD (KV L2-resident)
    const int rest = bid >> 3;
    const int sp   = rest % SPLIT;
    const int qblk = rest / SPLIT;
    const int q0   = qblk * 128 + w * 32;

    const int TPS = NTILE / SPLIT;
    const int kt0 = sp * TPS;

    const float SCL = 0.125f * 1.4426950408889634f;  // 1/sqrt(64) * log2(e)

    // Q fragments from f32 (scale folded): qf[u][c] = Q[q0+16u+lc][32c+8h+e]*SCL
    v8s qf[2][2];
    #pragma unroll
    for (int u = 0; u < 2; ++u) {
        const float* qrow = Q + ((size_t)b * NS + q0 + 16 * u + lc) * ND + 8 * h;
        #pragma unroll
        for (int c = 0; c < 2; ++c) {
            v4f x0 = *(const v4f*)(qrow + 32 * c);
            v4f x1 = *(const v4f*)(qrow + 32 * c + 4);
            qf[u][c] = pk8(x0 * SCL, x1 * SCL);
        }
    }

    v4f o[2][4];
    #pragma unroll
    for (int u = 0; u < 2; ++u)
        #pragma unroll
        for (int g = 0; g < 4; ++g) o[u][g] = (v4f){0.f, 0.f, 0.f, 0.f};
    float m[2]    = {-INFINITY, -INFINITY};
    float lsum[2] = {0.f, 0.f};

    auto stage = [&](int kt, int buf) {
        const size_t kb = ((size_t)b * NTILE + kt) * 4096 + w * 1024 + lane * 8;
        short* kd = &Ksh[buf][w * 1024];
        short* vd = &Vsh[buf][w * 1024];
        gl16(Kbf + kb,       kd);
        gl16(Kbf + kb + 512, kd + 512);
        gl16(Vtb + kb,       vd);
        gl16(Vtb + kb + 512, vd + 512);
    };

    stage(kt0, 0);

    auto body = [&](int i, int cur) {
        __syncthreads();   // compiler drains vmcnt(0): buf[cur] staged by all waves
        if (i + 1 < TPS) stage(kt0 + i + 1, cur ^ 1);

        // ---- S^T = K Q^T: lane holds scores for query lc, keys 16g+4h+r ----
        v4f a[2][4];
        __builtin_amdgcn_s_setprio(1);
        #pragma unroll
        for (int g = 0; g < 4; ++g) {
            a[0][g] = (v4f){0.f, 0.f, 0.f, 0.f};
            a[1][g] = (v4f){0.f, 0.f, 0.f, 0.f};
            const int row = 16 * g + lc;
            #pragma unroll
            for (int c = 0; c < 2; ++c) {
                v8s ka = *(const v8s*)&Ksh[cur][row * 64 + (((4 * c + h) ^ lw) << 3)];
                a[0][g] = __builtin_amdgcn_mfma_f32_16x16x32_bf16(ka, qf[0][c], a[0][g], 0, 0, 0);
                a[1][g] = __builtin_amdgcn_mfma_f32_16x16x32_bf16(ka, qf[1][c], a[1][g], 0, 0, 0);
            }
        }
        __builtin_amdgcn_s_setprio(0);

        // ---- online softmax (log2 domain), deferred rescale THR=8;
        //      exp2 packs straight into bf16 B-fragments (no f32 p array) ----
        union PB { v4s q[2]; v8s v; } pb[2][2];
        #pragma unroll
        for (int u = 0; u < 2; ++u) {
            float x0 = fmaxf(fmaxf(a[u][0][0], a[u][0][1]), a[u][0][2]);
            float x1 = fmaxf(fmaxf(a[u][0][3], a[u][1][0]), a[u][1][1]);
            float x2 = fmaxf(fmaxf(a[u][1][2], a[u][1][3]), a[u][2][0]);
            float x3 = fmaxf(fmaxf(a[u][2][1], a[u][2][2]), a[u][2][3]);
            float x4 = fmaxf(fmaxf(a[u][3][0], a[u][3][1]), a[u][3][2]);
            float pm = fmaxf(fmaxf(fmaxf(x0, x1), fmaxf(x2, x3)),
                             fmaxf(x4, a[u][3][3]));
            pm = fmaxf(pm, __shfl_xor(pm, 16));
            pm = fmaxf(pm, __shfl_xor(pm, 32));
            if (__any(pm > m[u] + 8.0f)) {
                float mn = fmaxf(m[u], pm);
                float al = __builtin_amdgcn_exp2f(m[u] - mn);   // first tile: 0
                #pragma unroll
                for (int g = 0; g < 4; ++g) o[u][g] = o[u][g] * al;
                lsum[u] *= al;
                m[u] = mn;
            }
            float rs = 0.f;
            #pragma unroll
            for (int g = 0; g < 4; ++g) {
                float e0 = __builtin_amdgcn_exp2f(a[u][g][0] - m[u]);
                float e1 = __builtin_amdgcn_exp2f(a[u][g][1] - m[u]);
                float e2 = __builtin_amdgcn_exp2f(a[u][g][2] - m[u]);
                float e3 = __builtin_amdgcn_exp2f(a[u][g][3] - m[u]);
                rs += (e0 + e1) + (e2 + e3);
                pb[u][g >> 1].q[g & 1] = pk4(e0, e1, e2, e3);
            }
            lsum[u] += rs;   // h-partial; reduced in epilogue
        }

        // ---- O^T += V^T P^T (P^T from registers, slot-matched V reads) ----
        __builtin_amdgcn_s_setprio(1);
        #pragma unroll
        for (int c2 = 0; c2 < 2; ++c2) {
            #pragma unroll
            for (int g = 0; g < 4; ++g) {
                const int row = 16 * g + lc;
                const int G0 = (4 * c2 + (h >> 1)) ^ lw;
                const int G1 = (4 * c2 + 2 + (h >> 1)) ^ lw;
                union PB va;
                va.q[0] = *(const v4s*)&Vsh[cur][row * 64 + (G0 << 3) + 4 * (h & 1)];
                va.q[1] = *(const v4s*)&Vsh[cur][row * 64 + (G1 << 3) + 4 * (h & 1)];
                o[0][g] = __builtin_amdgcn_mfma_f32_16x16x32_bf16(va.v, pb[0][c2].v, o[0][g], 0, 0, 0);
                o[1][g] = __builtin_amdgcn_mfma_f32_16x16x32_bf16(va.v, pb[1][c2].v, o[1][g], 0, 0, 0);
            }
        }
        __builtin_amdgcn_s_setprio(0);
    };

    for (int i = 0; i < TPS; i += 2) { body(i, 0); body(i + 1, 1); }

    // ---- epilogue: reduce lsum across h-lanes, normalize, store ----
    #pragma unroll
    for (int u = 0; u < 2; ++u) {
        float ls = lsum[u];
        ls += __shfl_xor(ls, 16);
        ls += __shfl_xor(ls, 32);
        const float inv = 1.0f / ls;
        const int q = q0 + 16 * u + lc;
        if constexpr (SPLIT == 1) {
            float* orow = O + ((size_t)b * NS + q) * ND;
            #pragma unroll
            for (int g = 0; g < 4; ++g) {
                v4f rr = o[u][g] * inv;
                *(v4f*)(orow + 16 * g + 4 * h) = rr;
            }
        } else {
            // normalized bf16 partial + (m, l) stats
            short* op = Opart + ((size_t)sp * NROW + (size_t)b * NS + q) * ND;
            #pragma unroll
            for (int g = 0; g < 4; ++g) {
                v4f rr = o[u][g] * inv;
                *(v4s*)(op + 16 * g + 4 * h) = pk4(rr[0], rr[1], rr[2], rr[3]);
            }
            if (h == 0) {
                float2 st; st.x = m[u]; st.y = ls;
                stats[(size_t)sp * NROW + (size_t)b * NS + q] = st;
            }
        }
    }
}

// ---- split-K combine: O = sum_s w_s * Obar_s / sum_s w_s, w_s = 2^(m_s-M) l_s ----
template <int SPLIT>
__global__ __launch_bounds__(256) void fa_combine(const short* __restrict__ Opart,
        const float2* __restrict__ stats, float* __restrict__ O) {
    const int idx = blockIdx.x * 256 + threadIdx.x;
    const int row = idx >> 3;
    const int d8  = (idx & 7) * 8;
    float2 st[SPLIT];
    float M = -INFINITY;
    #pragma unroll
    for (int s = 0; s < SPLIT; ++s) {
        st[s] = stats[(size_t)s * NROW + row];
        M = fmaxf(M, st[s].x);
    }
    float wt[SPLIT], wsum = 0.f;
    #pragma unroll
    for (int s = 0; s < SPLIT; ++s) {
        wt[s] = exp2f(st[s].x - M) * st[s].y;
        wsum += wt[s];
    }
    float acc[8] = {0.f, 0.f, 0.f, 0.f, 0.f, 0.f, 0.f, 0.f};
    #pragma unroll
    for (int s = 0; s < SPLIT; ++s) {
        v8s x = *(const v8s*)&Opart[((size_t)s * NROW + row) * ND + d8];
        #pragma unroll
        for (int j = 0; j < 8; ++j) acc[j] += wt[s] * b2f(x[j]);
    }
    const float inv = 1.0f / wsum;
    v4f r0, r1;
    #pragma unroll
    for (int j = 0; j < 4; ++j) { r0[j] = acc[j] * inv; r1[j] = acc[4 + j] * inv; }
    *(v4f*)&O[(size_t)row * ND + d8]     = r0;
    *(v4f*)&O[(size_t)row * ND + d8 + 4] = r1;
}

// ---- no-workspace fallback (R2 structure, inline f32->bf16 staging) ----
__global__ __launch_bounds__(256) void fa_fallback(
        const float* __restrict__ Q, const float* __restrict__ K,
        const float* __restrict__ V, float* __restrict__ O) {
    __shared__ short Ksh[64][72];
    __shared__ short Vsh[64][72];
    const int t = threadIdx.x;
    const int lane = t & 63;
    const int w = t >> 6;
    const int lc = lane & 15;
    const int h  = lane >> 4;
    const int b  = blockIdx.x & 7;
    const int q0 = (blockIdx.x >> 3) * 128 + w * 32;
    const float SCL = 0.125f * 1.4426950408889634f;
    v8s qf[2][2];
    #pragma unroll
    for (int u = 0; u < 2; ++u) {
        const float* qrow = Q + ((size_t)b * NS + q0 + 16 * u + lc) * ND + 8 * h;
        #pragma unroll
        for (int c = 0; c < 2; ++c) {
            v4f x0 = *(const v4f*)(qrow + 32 * c);
            v4f x1 = *(const v4f*)(qrow + 32 * c + 4);
            qf[u][c] = pk8(x0 * SCL, x1 * SCL);
        }
    }
    v4f o[2][4];
    #pragma unroll
    for (int u = 0; u < 2; ++u)
        #pragma unroll
        for (int g = 0; g < 4; ++g) o[u][g] = (v4f){0.f, 0.f, 0.f, 0.f};
    float m[2] = {-INFINITY, -INFINITY};
    float lsum[2] = {0.f, 0.f};
    for (int kt = 0; kt < NTILE; ++kt) {
        const int k0 = kt * 64;
        __syncthreads();
        #pragma unroll
        for (int i = 0; i < 4; ++i) {
            int n = i * 256 + t;
            int row = n >> 4, c4 = (n & 15) * 4;
            v4f x = *(const v4f*)(K + ((size_t)b * NS + k0 + row) * ND + c4);
            *(v4s*)&Ksh[row][c4] = pk4(x[0], x[1], x[2], x[3]);
        }
        const int sr = t >> 4, sc4 = t & 15;
        float xv[4][4];
        #pragma unroll
        for (int i = 0; i < 4; ++i) {
            v4f x = *(const v4f*)(V + ((size_t)b * NS + k0 + sr * 4 + i) * ND + sc4 * 4);
            xv[i][0] = x[0]; xv[i][1] = x[1]; xv[i][2] = x[2]; xv[i][3] = x[3];
        }
        #pragma unroll
        for (int j = 0; j < 4; ++j)
            *(v4s*)&Vsh[sc4 * 4 + j][sr * 4] = pk4(xv[0][j], xv[1][j], xv[2][j], xv[3][j]);
        __syncthreads();
        float p[2][4][4];
        #pragma unroll
        for (int g = 0; g < 4; ++g) {
            v4f a0 = (v4f){0.f, 0.f, 0.f, 0.f};
            v4f a1 = (v4f){0.f, 0.f, 0.f, 0.f};
            #pragma unroll
            for (int c = 0; c < 2; ++c) {
                v8s ka = *(const v8s*)&Ksh[16 * g + lc][32 * c + 8 * h];
                a0 = __builtin_amdgcn_mfma_f32_16x16x32_bf16(ka, qf[0][c], a0, 0, 0, 0);
                a1 = __builtin_amdgcn_mfma_f32_16x16x32_bf16(ka, qf[1][c], a1, 0, 0, 0);
            }
            #pragma unroll
            for (int r = 0; r < 4; ++r) { p[0][g][r] = a0[r]; p[1][g][r] = a1[r]; }
        }
        #pragma unroll
        for (int u = 0; u < 2; ++u) {
            float pm = p[u][0][0];
            #pragma unroll
            for (int g = 0; g < 4; ++g)
                #pragma unroll
                for (int r = 0; r < 4; ++r) pm = fmaxf(pm, p[u][g][r]);
            pm = fmaxf(pm, __shfl_xor(pm, 16));
            pm = fmaxf(pm, __shfl_xor(pm, 32));
            if (__any(pm > m[u] + 8.0f)) {
                float mn = fmaxf(m[u], pm);
                float al = __builtin_amdgcn_exp2f(m[u] - mn);
                #pragma unroll
                for (int g = 0; g < 4; ++g) o[u][g] = o[u][g] * al;
                lsum[u] *= al;
                m[u] = mn;
            }
            float rs = 0.f;
            #pragma unroll
            for (int g = 0; g < 4; ++g)
                #pragma unroll
                for (int r = 0; r < 4; ++r) {
                    p[u][g][r] = __builtin_amdgcn_exp2f(p[u][g][r] - m[u]);
                    rs += p[u][g][r];
                }
            lsum[u] += rs;
        }
        #pragma unroll
        for (int c2 = 0; c2 < 2; ++c2) {
            union { v4s q[2]; v8s v; } pb0, pb1;
            pb0.q[0] = pk4(p[0][2*c2][0],   p[0][2*c2][1],   p[0][2*c2][2],   p[0][2*c2][3]);
            pb0.q[1] = pk4(p[0][2*c2+1][0], p[0][2*c2+1][1], p[0][2*c2+1][2], p[0][2*c2+1][3]);
            pb1.q[0] = pk4(p[1][2*c2][0],   p[1][2*c2][1],   p[1][2*c2][2],   p[1][2*c2][3]);
            pb1.q[1] = pk4(p[1][2*c2+1][0], p[1][2*c2+1][1], p[1][2*c2+1][2], p[1][2*c2+1][3]);
            #pragma unroll
            for (int g = 0; g < 4; ++g) {
                union { v4s q[2]; v8s v; } va;
                va.q[0] = *(const v4s*)&Vsh[16 * g + lc][32 * c2 + 4 * h];
                va.q[1] = *(const v4s*)&Vsh[16 * g + lc][32 * c2 + 16 + 4 * h];
                o[0][g] = __builtin_amdgcn_mfma_f32_16x16x32_bf16(va.v, pb0.v, o[0][g], 0, 0, 0);
                o[1][g] = __builtin_amdgcn_mfma_f32_16x16x32_bf16(va.v, pb1.v, o[1][g], 0, 0, 0);
            }
        }
    }
    #pragma unroll
    for (int u = 0; u < 2; ++u) {
        float ls = lsum[u];
        ls += __shfl_xor(ls, 16);
        ls += __shfl_xor(ls, 32);
        float inv = 1.0f / ls;
        float* orow = O + ((size_t)b * NS + q0 + 16 * u + lc) * ND;
        #pragma unroll
        for (int g = 0; g < 4; ++g) {
            v4f rr = o[u][g] * inv;
            *(v4f*)(orow + 16 * g + 4 * h) = rr;
        }
    }
}

extern "C" void kernel_launch(void* const* d_in, const int* in_sizes, int n_in,
                              void* d_out, int out_size, void* d_ws, size_t ws_size,
                              hipStream_t stream) {
    const float* q = (const float*)d_in[0];
    const float* k = (const float*)d_in[1];
    const float* v = (const float*)d_in[2];
    float* out = (float*)d_out;

    const size_t tot   = (size_t)NB * NS * ND;                        // 2,097,152
    const size_t kv    = 2 * tot * sizeof(short);                     // 8 MB
    const size_t per_s = tot * sizeof(short) + (size_t)NROW * sizeof(float2);
    const size_t need8 = kv + 8 * per_s;                              // ~42 MB
    const size_t need4 = kv + 4 * per_s;                              // ~25 MB

    if (ws_size < kv) {
        hipLaunchKernelGGL(fa_fallback, dim3(NB * (NS / 128)), dim3(256), 0, stream,
                           q, k, v, out);
        return;
    }

    short* kbf = (short*)d_ws;
    short* vtb = kbf + tot;
    short* opart = vtb + tot;

    hipLaunchKernelGGL(prep_kv, dim3(1536), dim3(256), 0, stream, k, v, kbf, vtb);

    if (ws_size >= need8) {
        float2* stats = (float2*)(opart + 8 * tot);
        hipLaunchKernelGGL(fa_main<8>, dim3(NB * 32 * 8), dim3(256), 0, stream,
                           q, kbf, vtb, out, opart, stats);
        hipLaunchKernelGGL(fa_combine<8>, dim3(NROW * 8 / 256), dim3(256), 0, stream,
                           opart, stats, out);
    } else if (ws_size >= need4) {
        float2* stats = (float2*)(opart + 4 * tot);
        hipLaunchKernelGGL(fa_main<4>, dim3(NB * 32 * 4), dim3(256), 0, stream,
                           q, kbf, vtb, out, opart, stats);
        hipLaunchKernelGGL(fa_combine<4>, dim3(NROW * 8 / 256), dim3(256), 0, stream,
                           opart, stats, out);
    } else {
        hipLaunchKernelGGL(fa_main<1>, dim3(NB * 32), dim3(256), 0, stream,
                           q, kbf, vtb, out, (short*)nullptr, (float2*)nullptr);
    }
}

// Round 5
// 71.890 us; speedup vs baseline: 2.1112x; 2.1112x over previous
//
#include <hip/hip_runtime.h>
#include <hip/hip_bf16.h>

#define NB 8
#define NS 4096
#define ND 64
#define NROW (NB * NS)
#define NTILE (NS / 64)

typedef short v4s __attribute__((ext_vector_type(4)));
typedef short v8s __attribute__((ext_vector_type(8)));
typedef float v4f __attribute__((ext_vector_type(4)));

static __device__ __forceinline__ v4s pk4(float a, float b, float c, float d) {
    union { __hip_bfloat162 h[2]; v4s v; } u;
    float2 p0; p0.x = a; p0.y = b;
    float2 p1; p1.x = c; p1.y = d;
    u.h[0] = __float22bfloat162_rn(p0);
    u.h[1] = __float22bfloat162_rn(p1);
    return u.v;
}
static __device__ __forceinline__ v8s pk8(v4f x0, v4f x1) {
    union { v4s q[2]; v8s v; } u;
    u.q[0] = pk4(x0[0], x0[1], x0[2], x0[3]);
    u.q[1] = pk4(x1[0], x1[1], x1[2], x1[3]);
    return u.v;
}
static __device__ __forceinline__ float b2f(short s) {
    return __uint_as_float(((unsigned)(unsigned short)s) << 16);
}

__device__ __forceinline__ void gl16(const void* g, void* s) {
    __builtin_amdgcn_global_load_lds(
        (const __attribute__((address_space(1))) void*)g,
        (__attribute__((address_space(3))) void*)s, 16, 0, 0);
}

// ---- fused prepass: K -> bf16 swizzled tiles; V -> bf16 transposed tiles ----
__global__ __launch_bounds__(256) void prep_kv(const float* __restrict__ K,
        const float* __restrict__ V, short* __restrict__ Kb,
        short* __restrict__ Vt) {
    __shared__ short T[64][72];
    const int t = threadIdx.x;
    if (blockIdx.x < 1024) {
        // K: per-64-key-tile stream, 16B granules XOR-swizzled by row
        size_t n = (size_t)blockIdx.x * 256 + t;
        int g = (int)(n & 7);
        size_t r = n >> 3;
        int row = (int)(r & 63);
        size_t tile = r >> 6;
        v4f x0 = *(const v4f*)(K + n * 8);
        v4f x1 = *(const v4f*)(K + n * 8 + 4);
        *(v8s*)&Kb[tile * 4096 + row * 64 + ((g ^ (row & 7)) << 3)] = pk8(x0, x1);
    } else {
        // V: transpose [d][key] per tile, swizzled granules
        const int bt = blockIdx.x - 1024;
        const int b  = bt >> 6;
        const int s0 = (bt & 63) * 64;
        #pragma unroll
        for (int i = 0; i < 2; ++i) {
            int n = i * 256 + t;
            int r = n >> 3, c8 = (n & 7) * 8;
            const float* src = V + ((size_t)b * NS + s0 + r) * ND + c8;
            v4f x0 = *(const v4f*)src;
            v4f x1 = *(const v4f*)(src + 4);
            *(v8s*)&T[r][c8] = pk8(x0, x1);
        }
        __syncthreads();
        #pragma unroll
        for (int i = 0; i < 2; ++i) {
            int n = i * 256 + t;
            int d = n >> 3, kg = n & 7;
            v8s a;
            #pragma unroll
            for (int j = 0; j < 8; ++j) a[j] = T[kg * 8 + j][d];
            *(v8s*)&Vt[(size_t)bt * 4096 + d * 64 + ((kg ^ (d & 7)) << 3)] = a;
        }
    }
}

// ---- main flash kernel: 32 q/wave, 128 q/block, split-K ----
// launch_bounds(256,4): VGPR cap 128 -> NO SPILL (R4's (256,5) forced 48 VGPR
// and 600 MB of scratch traffic). Live state ~90 VGPR.
template <int SPLIT>
__global__ __launch_bounds__(256, 4) void fa_main(
        const float* __restrict__ Q, const short* __restrict__ Kbf,
        const short* __restrict__ Vtb, float* __restrict__ O,
        short* __restrict__ Opart, float2* __restrict__ stats) {
    __shared__ short Ksh[2][4096];
    __shared__ short Vsh[2][4096];

    const int t    = threadIdx.x;
    const int lane = t & 63;
    const int w    = t >> 6;
    const int lc   = lane & 15;
    const int h    = lane >> 4;
    const int lw   = lc & 7;

    const int bid  = blockIdx.x;
    const int b    = bid & 7;                 // batch -> XCD (KV L2-resident)
    const int rest = bid >> 3;
    const int sp   = rest % SPLIT;
    const int qblk = rest / SPLIT;
    const int q0   = qblk * 128 + w * 32;

    const int TPS = NTILE / SPLIT;
    const int kt0 = sp * TPS;

    const float SCL = 0.125f * 1.4426950408889634f;  // 1/sqrt(64) * log2(e)

    // Q fragments from f32 (scale folded): qf[u][c] = Q[q0+16u+lc][32c+8h+e]*SCL
    v8s qf[2][2];
    #pragma unroll
    for (int u = 0; u < 2; ++u) {
        const float* qrow = Q + ((size_t)b * NS + q0 + 16 * u + lc) * ND + 8 * h;
        #pragma unroll
        for (int c = 0; c < 2; ++c) {
            v4f x0 = *(const v4f*)(qrow + 32 * c);
            v4f x1 = *(const v4f*)(qrow + 32 * c + 4);
            qf[u][c] = pk8(x0 * SCL, x1 * SCL);
        }
    }

    v4f o[2][4];
    #pragma unroll
    for (int u = 0; u < 2; ++u)
        #pragma unroll
        for (int g = 0; g < 4; ++g) o[u][g] = (v4f){0.f, 0.f, 0.f, 0.f};
    float m[2]    = {-INFINITY, -INFINITY};
    float lsum[2] = {0.f, 0.f};

    auto stage = [&](int kt, int buf) {
        const size_t kb = ((size_t)b * NTILE + kt) * 4096 + w * 1024 + lane * 8;
        short* kd = &Ksh[buf][w * 1024];
        short* vd = &Vsh[buf][w * 1024];
        gl16(Kbf + kb,       kd);
        gl16(Kbf + kb + 512, kd + 512);
        gl16(Vtb + kb,       vd);
        gl16(Vtb + kb + 512, vd + 512);
    };

    stage(kt0, 0);

    auto body = [&](int i, int cur) {
        __syncthreads();   // compiler drains vmcnt(0): buf[cur] staged by all waves
        if (i + 1 < TPS) stage(kt0 + i + 1, cur ^ 1);

        // ---- S^T = K Q^T: lane holds scores for query lc, keys 16g+4h+r ----
        v4f a[2][4];
        __builtin_amdgcn_s_setprio(1);
        #pragma unroll
        for (int g = 0; g < 4; ++g) {
            a[0][g] = (v4f){0.f, 0.f, 0.f, 0.f};
            a[1][g] = (v4f){0.f, 0.f, 0.f, 0.f};
            const int row = 16 * g + lc;
            #pragma unroll
            for (int c = 0; c < 2; ++c) {
                v8s ka = *(const v8s*)&Ksh[cur][row * 64 + (((4 * c + h) ^ lw) << 3)];
                a[0][g] = __builtin_amdgcn_mfma_f32_16x16x32_bf16(ka, qf[0][c], a[0][g], 0, 0, 0);
                a[1][g] = __builtin_amdgcn_mfma_f32_16x16x32_bf16(ka, qf[1][c], a[1][g], 0, 0, 0);
            }
        }
        __builtin_amdgcn_s_setprio(0);

        // ---- online softmax (log2 domain), deferred rescale THR=8;
        //      exp2 packs straight into bf16 B-fragments (no f32 p array) ----
        union PB { v4s q[2]; v8s v; } pb[2][2];
        #pragma unroll
        for (int u = 0; u < 2; ++u) {
            float x0 = fmaxf(fmaxf(a[u][0][0], a[u][0][1]), a[u][0][2]);
            float x1 = fmaxf(fmaxf(a[u][0][3], a[u][1][0]), a[u][1][1]);
            float x2 = fmaxf(fmaxf(a[u][1][2], a[u][1][3]), a[u][2][0]);
            float x3 = fmaxf(fmaxf(a[u][2][1], a[u][2][2]), a[u][2][3]);
            float x4 = fmaxf(fmaxf(a[u][3][0], a[u][3][1]), a[u][3][2]);
            float pm = fmaxf(fmaxf(fmaxf(x0, x1), fmaxf(x2, x3)),
                             fmaxf(x4, a[u][3][3]));
            pm = fmaxf(pm, __shfl_xor(pm, 16));
            pm = fmaxf(pm, __shfl_xor(pm, 32));
            if (__any(pm > m[u] + 8.0f)) {
                float mn = fmaxf(m[u], pm);
                float al = __builtin_amdgcn_exp2f(m[u] - mn);   // first tile: 0
                #pragma unroll
                for (int g = 0; g < 4; ++g) o[u][g] = o[u][g] * al;
                lsum[u] *= al;
                m[u] = mn;
            }
            float rs = 0.f;
            #pragma unroll
            for (int g = 0; g < 4; ++g) {
                float e0 = __builtin_amdgcn_exp2f(a[u][g][0] - m[u]);
                float e1 = __builtin_amdgcn_exp2f(a[u][g][1] - m[u]);
                float e2 = __builtin_amdgcn_exp2f(a[u][g][2] - m[u]);
                float e3 = __builtin_amdgcn_exp2f(a[u][g][3] - m[u]);
                rs += (e0 + e1) + (e2 + e3);
                pb[u][g >> 1].q[g & 1] = pk4(e0, e1, e2, e3);
            }
            lsum[u] += rs;   // h-partial; reduced in epilogue
        }

        // ---- O^T += V^T P^T (P^T from registers, slot-matched V reads) ----
        __builtin_amdgcn_s_setprio(1);
        #pragma unroll
        for (int c2 = 0; c2 < 2; ++c2) {
            #pragma unroll
            for (int g = 0; g < 4; ++g) {
                const int row = 16 * g + lc;
                const int G0 = (4 * c2 + (h >> 1)) ^ lw;
                const int G1 = (4 * c2 + 2 + (h >> 1)) ^ lw;
                union PB va;
                va.q[0] = *(const v4s*)&Vsh[cur][row * 64 + (G0 << 3) + 4 * (h & 1)];
                va.q[1] = *(const v4s*)&Vsh[cur][row * 64 + (G1 << 3) + 4 * (h & 1)];
                o[0][g] = __builtin_amdgcn_mfma_f32_16x16x32_bf16(va.v, pb[0][c2].v, o[0][g], 0, 0, 0);
                o[1][g] = __builtin_amdgcn_mfma_f32_16x16x32_bf16(va.v, pb[1][c2].v, o[1][g], 0, 0, 0);
            }
        }
        __builtin_amdgcn_s_setprio(0);
    };

    for (int i = 0; i < TPS; i += 2) { body(i, 0); body(i + 1, 1); }

    // ---- epilogue: reduce lsum across h-lanes, normalize, store ----
    #pragma unroll
    for (int u = 0; u < 2; ++u) {
        float ls = lsum[u];
        ls += __shfl_xor(ls, 16);
        ls += __shfl_xor(ls, 32);
        const float inv = 1.0f / ls;
        const int q = q0 + 16 * u + lc;
        if constexpr (SPLIT == 1) {
            float* orow = O + ((size_t)b * NS + q) * ND;
            #pragma unroll
            for (int g = 0; g < 4; ++g) {
                v4f rr = o[u][g] * inv;
                *(v4f*)(orow + 16 * g + 4 * h) = rr;
            }
        } else {
            // normalized bf16 partial + (m, l) stats
            short* op = Opart + ((size_t)sp * NROW + (size_t)b * NS + q) * ND;
            #pragma unroll
            for (int g = 0; g < 4; ++g) {
                v4f rr = o[u][g] * inv;
                *(v4s*)(op + 16 * g + 4 * h) = pk4(rr[0], rr[1], rr[2], rr[3]);
            }
            if (h == 0) {
                float2 st; st.x = m[u]; st.y = ls;
                stats[(size_t)sp * NROW + (size_t)b * NS + q] = st;
            }
        }
    }
}

// ---- split-K combine: O = sum_s w_s * Obar_s / sum_s w_s, w_s = 2^(m_s-M) l_s ----
template <int SPLIT>
__global__ __launch_bounds__(256) void fa_combine(const short* __restrict__ Opart,
        const float2* __restrict__ stats, float* __restrict__ O) {
    const int idx = blockIdx.x * 256 + threadIdx.x;
    const int row = idx >> 3;
    const int d8  = (idx & 7) * 8;
    float2 st[SPLIT];
    float M = -INFINITY;
    #pragma unroll
    for (int s = 0; s < SPLIT; ++s) {
        st[s] = stats[(size_t)s * NROW + row];
        M = fmaxf(M, st[s].x);
    }
    float wt[SPLIT], wsum = 0.f;
    #pragma unroll
    for (int s = 0; s < SPLIT; ++s) {
        wt[s] = exp2f(st[s].x - M) * st[s].y;
        wsum += wt[s];
    }
    float acc[8] = {0.f, 0.f, 0.f, 0.f, 0.f, 0.f, 0.f, 0.f};
    #pragma unroll
    for (int s = 0; s < SPLIT; ++s) {
        v8s x = *(const v8s*)&Opart[((size_t)s * NROW + row) * ND + d8];
        #pragma unroll
        for (int j = 0; j < 8; ++j) acc[j] += wt[s] * b2f(x[j]);
    }
    const float inv = 1.0f / wsum;
    v4f r0, r1;
    #pragma unroll
    for (int j = 0; j < 4; ++j) { r0[j] = acc[j] * inv; r1[j] = acc[4 + j] * inv; }
    *(v4f*)&O[(size_t)row * ND + d8]     = r0;
    *(v4f*)&O[(size_t)row * ND + d8 + 4] = r1;
}

// ---- no-workspace fallback (R2 structure, inline f32->bf16 staging) ----
__global__ __launch_bounds__(256) void fa_fallback(
        const float* __restrict__ Q, const float* __restrict__ K,
        const float* __restrict__ V, float* __restrict__ O) {
    __shared__ short Ksh[64][72];
    __shared__ short Vsh[64][72];
    const int t = threadIdx.x;
    const int lane = t & 63;
    const int w = t >> 6;
    const int lc = lane & 15;
    const int h  = lane >> 4;
    const int b  = blockIdx.x & 7;
    const int q0 = (blockIdx.x >> 3) * 128 + w * 32;
    const float SCL = 0.125f * 1.4426950408889634f;
    v8s qf[2][2];
    #pragma unroll
    for (int u = 0; u < 2; ++u) {
        const float* qrow = Q + ((size_t)b * NS + q0 + 16 * u + lc) * ND + 8 * h;
        #pragma unroll
        for (int c = 0; c < 2; ++c) {
            v4f x0 = *(const v4f*)(qrow + 32 * c);
            v4f x1 = *(const v4f*)(qrow + 32 * c + 4);
            qf[u][c] = pk8(x0 * SCL, x1 * SCL);
        }
    }
    v4f o[2][4];
    #pragma unroll
    for (int u = 0; u < 2; ++u)
        #pragma unroll
        for (int g = 0; g < 4; ++g) o[u][g] = (v4f){0.f, 0.f, 0.f, 0.f};
    float m[2] = {-INFINITY, -INFINITY};
    float lsum[2] = {0.f, 0.f};
    for (int kt = 0; kt < NTILE; ++kt) {
        const int k0 = kt * 64;
        __syncthreads();
        #pragma unroll
        for (int i = 0; i < 4; ++i) {
            int n = i * 256 + t;
            int row = n >> 4, c4 = (n & 15) * 4;
            v4f x = *(const v4f*)(K + ((size_t)b * NS + k0 + row) * ND + c4);
            *(v4s*)&Ksh[row][c4] = pk4(x[0], x[1], x[2], x[3]);
        }
        const int sr = t >> 4, sc4 = t & 15;
        float xv[4][4];
        #pragma unroll
        for (int i = 0; i < 4; ++i) {
            v4f x = *(const v4f*)(V + ((size_t)b * NS + k0 + sr * 4 + i) * ND + sc4 * 4);
            xv[i][0] = x[0]; xv[i][1] = x[1]; xv[i][2] = x[2]; xv[i][3] = x[3];
        }
        #pragma unroll
        for (int j = 0; j < 4; ++j)
            *(v4s*)&Vsh[sc4 * 4 + j][sr * 4] = pk4(xv[0][j], xv[1][j], xv[2][j], xv[3][j]);
        __syncthreads();
        float p[2][4][4];
        #pragma unroll
        for (int g = 0; g < 4; ++g) {
            v4f a0 = (v4f){0.f, 0.f, 0.f, 0.f};
            v4f a1 = (v4f){0.f, 0.f, 0.f, 0.f};
            #pragma unroll
            for (int c = 0; c < 2; ++c) {
                v8s ka = *(const v8s*)&Ksh[16 * g + lc][32 * c + 8 * h];
                a0 = __builtin_amdgcn_mfma_f32_16x16x32_bf16(ka, qf[0][c], a0, 0, 0, 0);
                a1 = __builtin_amdgcn_mfma_f32_16x16x32_bf16(ka, qf[1][c], a1, 0, 0, 0);
            }
            #pragma unroll
            for (int r = 0; r < 4; ++r) { p[0][g][r] = a0[r]; p[1][g][r] = a1[r]; }
        }
        #pragma unroll
        for (int u = 0; u < 2; ++u) {
            float pm = p[u][0][0];
            #pragma unroll
            for (int g = 0; g < 4; ++g)
                #pragma unroll
                for (int r = 0; r < 4; ++r) pm = fmaxf(pm, p[u][g][r]);
            pm = fmaxf(pm, __shfl_xor(pm, 16));
            pm = fmaxf(pm, __shfl_xor(pm, 32));
            if (__any(pm > m[u] + 8.0f)) {
                float mn = fmaxf(m[u], pm);
                float al = __builtin_amdgcn_exp2f(m[u] - mn);
                #pragma unroll
                for (int g = 0; g < 4; ++g) o[u][g] = o[u][g] * al;
                lsum[u] *= al;
                m[u] = mn;
            }
            float rs = 0.f;
            #pragma unroll
            for (int g = 0; g < 4; ++g)
                #pragma unroll
                for (int r = 0; r < 4; ++r) {
                    p[u][g][r] = __builtin_amdgcn_exp2f(p[u][g][r] - m[u]);
                    rs += p[u][g][r];
                }
            lsum[u] += rs;
        }
        #pragma unroll
        for (int c2 = 0; c2 < 2; ++c2) {
            union { v4s q[2]; v8s v; } pb0, pb1;
            pb0.q[0] = pk4(p[0][2*c2][0],   p[0][2*c2][1],   p[0][2*c2][2],   p[0][2*c2][3]);
            pb0.q[1] = pk4(p[0][2*c2+1][0], p[0][2*c2+1][1], p[0][2*c2+1][2], p[0][2*c2+1][3]);
            pb1.q[0] = pk4(p[1][2*c2][0],   p[1][2*c2][1],   p[1][2*c2][2],   p[1][2*c2][3]);
            pb1.q[1] = pk4(p[1][2*c2+1][0], p[1][2*c2+1][1], p[1][2*c2+1][2], p[1][2*c2+1][3]);
            #pragma unroll
            for (int g = 0; g < 4; ++g) {
                union { v4s q[2]; v8s v; } va;
                va.q[0] = *(const v4s*)&Vsh[16 * g + lc][32 * c2 + 4 * h];
                va.q[1] = *(const v4s*)&Vsh[16 * g + lc][32 * c2 + 16 + 4 * h];
                o[0][g] = __builtin_amdgcn_mfma_f32_16x16x32_bf16(va.v, pb0.v, o[0][g], 0, 0, 0);
                o[1][g] = __builtin_amdgcn_mfma_f32_16x16x32_bf16(va.v, pb1.v, o[1][g], 0, 0, 0);
            }
        }
    }
    #pragma unroll
    for (int u = 0; u < 2; ++u) {
        float ls = lsum[u];
        ls += __shfl_xor(ls, 16);
        ls += __shfl_xor(ls, 32);
        float inv = 1.0f / ls;
        float* orow = O + ((size_t)b * NS + q0 + 16 * u + lc) * ND;
        #pragma unroll
        for (int g = 0; g < 4; ++g) {
            v4f rr = o[u][g] * inv;
            *(v4f*)(orow + 16 * g + 4 * h) = rr;
        }
    }
}

extern "C" void kernel_launch(void* const* d_in, const int* in_sizes, int n_in,
                              void* d_out, int out_size, void* d_ws, size_t ws_size,
                              hipStream_t stream) {
    const float* q = (const float*)d_in[0];
    const float* k = (const float*)d_in[1];
    const float* v = (const float*)d_in[2];
    float* out = (float*)d_out;

    const size_t tot   = (size_t)NB * NS * ND;                        // 2,097,152
    const size_t kv    = 2 * tot * sizeof(short);                     // 8 MB
    const size_t per_s = tot * sizeof(short) + (size_t)NROW * sizeof(float2);
    const size_t need8 = kv + 8 * per_s;                              // ~42 MB
    const size_t need4 = kv + 4 * per_s;                              // ~25 MB

    if (ws_size < kv) {
        hipLaunchKernelGGL(fa_fallback, dim3(NB * (NS / 128)), dim3(256), 0, stream,
                           q, k, v, out);
        return;
    }

    short* kbf = (short*)d_ws;
    short* vtb = kbf + tot;
    short* opart = vtb + tot;

    hipLaunchKernelGGL(prep_kv, dim3(1536), dim3(256), 0, stream, k, v, kbf, vtb);

    if (ws_size >= need8) {
        float2* stats = (float2*)(opart + 8 * tot);
        hipLaunchKernelGGL(fa_main<8>, dim3(NB * 32 * 8), dim3(256), 0, stream,
                           q, kbf, vtb, out, opart, stats);
        hipLaunchKernelGGL(fa_combine<8>, dim3(NROW * 8 / 256), dim3(256), 0, stream,
                           opart, stats, out);
    } else if (ws_size >= need4) {
        float2* stats = (float2*)(opart + 4 * tot);
        hipLaunchKernelGGL(fa_main<4>, dim3(NB * 32 * 4), dim3(256), 0, stream,
                           q, kbf, vtb, out, opart, stats);
        hipLaunchKernelGGL(fa_combine<4>, dim3(NROW * 8 / 256), dim3(256), 0, stream,
                           opart, stats, out);
    } else {
        hipLaunchKernelGGL(fa_main<1>, dim3(NB * 32), dim3(256), 0, stream,
                           q, kbf, vtb, out, (short*)nullptr, (float2*)nullptr);
    }
}